// Round 7
// baseline (710.007 us; speedup 1.0000x reference)
//
#include <hip/hip_runtime.h>

// HSN layer: out = sigmoid( A0 @ (sig(A0 @ (x W1_00)) W2_00) + B1 @ (sig(B1^T @ (x W1_01)) W2_10) )
// C = 128 fixed. CSR-gather SpMM (no f32 atomics) + MFMA GEMMs.
// Intermediate features bf16. CSR build: fused 3-matrix two-level LDS counting
// sort. 11 dispatches total.
// R7 (SpMM = gather-latency-bound: VALU diet cut VALUBusy 85->77% with no dur
// change; FETCH 411MB = L2-miss/L3 traffic at 2.8 TB/s):
//   * adj bulk UNR 4->8 (8 KB of gathers in flight/wave, unmasked bulk loop)
//   * edge-side SpMM (avg 2 nnz/row): dual-row waves -- groups {0,1} row 2w,
//     {2,3} row 2w+1, xor-16 completes reduction; 2x group utilization.

#define CF 128
#define RB 64          // rows per bucket (2^RB_SHIFT)
#define RB_SHIFT 6
#define NPASSBLK 256   // blocks (chunks) per matrix in count/scatter passes
#define BT 512         // threads per count/scatter block

typedef __attribute__((ext_vector_type(8))) short bf16x8;
typedef __attribute__((ext_vector_type(4))) float f32x4;
typedef __attribute__((ext_vector_type(2))) float f32x2;

__device__ __forceinline__ unsigned short bf16rne(float f) {
  unsigned u = __float_as_uint(f);
  u += 0x7FFFu + ((u >> 16) & 1u);
  return (unsigned short)(u >> 16);
}
__device__ __forceinline__ void splitf(float f, short& h, short& l) {
  unsigned u = __float_as_uint(f);
  h = (short)(u >> 16);
  float fh = __uint_as_float(u & 0xFFFF0000u);
  float r = f - fh;
  l = (short)(__float_as_uint(r) >> 16);
}
__device__ __forceinline__ f32x2 bf2v(unsigned u) {
  f32x2 f;
  f.x = __uint_as_float(u << 16);
  f.y = __uint_as_float(u & 0xFFFF0000u);
  return f;
}

// ---------------------------------------------------------------------------
// Pack 4x W[128][128] f32 into mfma_f32_16x16x32_bf16 B-fragment order:
// frag[(s*8+t)*64+lane][j] = W[s*32+(lane>>4)*8+j][t*16+(lane&15)]
// ---------------------------------------------------------------------------
__global__ __launch_bounds__(256)
void pack_w4(const float* __restrict__ W0, const float* __restrict__ W1,
             const float* __restrict__ W2, const float* __restrict__ W3,
             short* __restrict__ wp) {
  const int w = blockIdx.x >> 3;
  const float* W = (w == 0) ? W0 : (w == 1) ? W1 : (w == 2) ? W2 : W3;
  short* hi = wp + (size_t)w * 32768;
  short* lo = hi + 16384;
  const int tid = (blockIdx.x & 7) * 256 + threadIdx.x;   // 0..2047
  const int lane = tid & 63;
  const int t = (tid >> 6) & 7;
  const int s = tid >> 9;
  const int n = t * 16 + (lane & 15);
  const int k0 = s * 32 + ((lane >> 4) << 3);
  short* hp = hi + (size_t)tid * 8;
  short* lp = lo + (size_t)tid * 8;
#pragma unroll
  for (int j = 0; j < 8; ++j) {
    short h, l;
    splitf(W[(size_t)(k0 + j) * CF + n], h, l);
    hp[j] = h;
    lp[j] = l;
  }
}

// ---------------------------------------------------------------------------
// GEMM bodies (device functions, called from fused range-dispatch kernels)
// ---------------------------------------------------------------------------
__device__ __forceinline__ void gemm_f32_body(const float* __restrict__ X,
                                              const short* __restrict__ Whi,
                                              const short* __restrict__ Wlo,
                                              unsigned short* __restrict__ Y,
                                              int M, int blk) {
  const int wave = threadIdx.x >> 6;
  const int lane = threadIdx.x & 63;
  const int mrow = lane & 15;
  const int quad = lane >> 4;
  const int row0 = blk * 64 + wave * 32;

  const bf16x8* WH = (const bf16x8*)Whi;
  const bf16x8* WL = (const bf16x8*)Wlo;

  f32x4 acc[2][8];
#pragma unroll
  for (int mt = 0; mt < 2; ++mt)
#pragma unroll
    for (int t = 0; t < 8; ++t) acc[mt][t] = (f32x4){0.f, 0.f, 0.f, 0.f};

  int rA0 = row0 + mrow;      if (rA0 > M - 1) rA0 = M - 1;
  int rA1 = row0 + 16 + mrow; if (rA1 > M - 1) rA1 = M - 1;
  const float* xp0 = X + (size_t)rA0 * CF + quad * 8;
  const float* xp1 = X + (size_t)rA1 * CF + quad * 8;

#pragma unroll
  for (int s = 0; s < 4; ++s) {
    bf16x8 Ah[2], Al[2];
    const float* p = xp0 + s * 32;
#pragma unroll
    for (int j = 0; j < 8; ++j) { short h, l; splitf(p[j], h, l); Ah[0][j] = h; Al[0][j] = l; }
    p = xp1 + s * 32;
#pragma unroll
    for (int j = 0; j < 8; ++j) { short h, l; splitf(p[j], h, l); Ah[1][j] = h; Al[1][j] = l; }
#pragma unroll
    for (int t = 0; t < 8; ++t) {
      const bf16x8 bh = WH[(s * 8 + t) * 64 + lane];
      const bf16x8 bl = WL[(s * 8 + t) * 64 + lane];
#pragma unroll
      for (int mt = 0; mt < 2; ++mt) {
        acc[mt][t] = __builtin_amdgcn_mfma_f32_16x16x32_bf16(Ah[mt], bh, acc[mt][t], 0, 0, 0);
        acc[mt][t] = __builtin_amdgcn_mfma_f32_16x16x32_bf16(Al[mt], bh, acc[mt][t], 0, 0, 0);
        acc[mt][t] = __builtin_amdgcn_mfma_f32_16x16x32_bf16(Ah[mt], bl, acc[mt][t], 0, 0, 0);
      }
    }
  }

#pragma unroll
  for (int mt = 0; mt < 2; ++mt)
#pragma unroll
    for (int reg = 0; reg < 4; ++reg) {
      const int r = row0 + mt * 16 + quad * 4 + reg;
      if (r < M) {
        unsigned short* yp = Y + (size_t)r * CF + mrow;
#pragma unroll
        for (int t = 0; t < 8; ++t) yp[t * 16] = bf16rne(acc[mt][t][reg]);
      }
    }
}

__device__ __forceinline__ void gemm_b16_body(const unsigned short* __restrict__ X,
                                              const short* __restrict__ Whi,
                                              const short* __restrict__ Wlo,
                                              unsigned short* __restrict__ Y,
                                              int M, int blk) {
  const int wave = threadIdx.x >> 6;
  const int lane = threadIdx.x & 63;
  const int mrow = lane & 15;
  const int quad = lane >> 4;
  const int row0 = blk * 64 + wave * 32;

  const bf16x8* WH = (const bf16x8*)Whi;
  const bf16x8* WL = (const bf16x8*)Wlo;

  f32x4 acc[2][8];
#pragma unroll
  for (int mt = 0; mt < 2; ++mt)
#pragma unroll
    for (int t = 0; t < 8; ++t) acc[mt][t] = (f32x4){0.f, 0.f, 0.f, 0.f};

  int rA0 = row0 + mrow;      if (rA0 > M - 1) rA0 = M - 1;
  int rA1 = row0 + 16 + mrow; if (rA1 > M - 1) rA1 = M - 1;
  const bf16x8* xp0 = (const bf16x8*)(X + (size_t)rA0 * CF + quad * 8);
  const bf16x8* xp1 = (const bf16x8*)(X + (size_t)rA1 * CF + quad * 8);

#pragma unroll
  for (int s = 0; s < 4; ++s) {
    bf16x8 A0 = xp0[s * 4];
    bf16x8 A1 = xp1[s * 4];
#pragma unroll
    for (int t = 0; t < 8; ++t) {
      const bf16x8 bh = WH[(s * 8 + t) * 64 + lane];
      const bf16x8 bl = WL[(s * 8 + t) * 64 + lane];
      acc[0][t] = __builtin_amdgcn_mfma_f32_16x16x32_bf16(A0, bh, acc[0][t], 0, 0, 0);
      acc[0][t] = __builtin_amdgcn_mfma_f32_16x16x32_bf16(A0, bl, acc[0][t], 0, 0, 0);
      acc[1][t] = __builtin_amdgcn_mfma_f32_16x16x32_bf16(A1, bh, acc[1][t], 0, 0, 0);
      acc[1][t] = __builtin_amdgcn_mfma_f32_16x16x32_bf16(A1, bl, acc[1][t], 0, 0, 0);
    }
  }

#pragma unroll
  for (int mt = 0; mt < 2; ++mt)
#pragma unroll
    for (int reg = 0; reg < 4; ++reg) {
      const int r = row0 + mt * 16 + quad * 4 + reg;
      if (r < M) {
        unsigned short* yp = Y + (size_t)r * CF + mrow;
#pragma unroll
        for (int t = 0; t < 8; ++t) yp[t * 16] = bf16rne(acc[mt][t][reg]);
      }
    }
}

// fused L1: blocks [0,g) -> Y0 = X@W00 ; [g,2g) -> Y1 = X@W01 (same X, M)
__global__ __launch_bounds__(128)
void gemm_f32_l1(const float* __restrict__ X,
                 const short* __restrict__ w00, const short* __restrict__ w01,
                 unsigned short* __restrict__ Y0, unsigned short* __restrict__ Y1,
                 int M, int g) {
  if ((int)blockIdx.x < g)
    gemm_f32_body(X, w00, w00 + 16384, Y0, M, blockIdx.x);
  else
    gemm_f32_body(X, w01, w01 + 16384, Y1, M, blockIdx.x - g);
}

// fused L2: blocks [0,gN) -> n1 = n1@W20 ; [gN,gN+gE) -> e1 = e1@W21
__global__ __launch_bounds__(128)
void gemm_b16_l2(unsigned short* __restrict__ n1, const short* __restrict__ w20,
                 unsigned short* __restrict__ e1, const short* __restrict__ w21,
                 int MN, int ME, int gN) {
  if ((int)blockIdx.x < gN)
    gemm_b16_body(n1, w20, w20 + 16384, n1, MN, blockIdx.x);
  else
    gemm_b16_body(e1, w21, w21 + 16384, e1, ME, blockIdx.x - gN);
}

// --------------------------- scan kernels ----------------------------------
__global__ __launch_bounds__(256)
void scan_block(const int* __restrict__ cnt, int* __restrict__ ptr,
                int* __restrict__ blksum, int n) {
  __shared__ int sdata[256];
  const int t = threadIdx.x;
  const int idx = blockIdx.x * 1024 + t * 4;
  int v[4];
#pragma unroll
  for (int k = 0; k < 4; ++k) v[k] = (idx + k < n) ? cnt[idx + k] : 0;
  int tsum = v[0] + v[1] + v[2] + v[3];
  sdata[t] = tsum;
  __syncthreads();
  for (int off = 1; off < 256; off <<= 1) {
    int x = (t >= off) ? sdata[t - off] : 0;
    __syncthreads();
    sdata[t] += x;
    __syncthreads();
  }
  if (t == 255) blksum[blockIdx.x] = sdata[255];
  int run = sdata[t] - tsum;
#pragma unroll
  for (int k = 0; k < 4; ++k) {
    if (idx + k < n) ptr[idx + k] = run;
    run += v[k];
  }
}

// exclusive scan of up to 2048 block sums, one 256-thread block.
__global__ __launch_bounds__(256)
void scan_sums(int* __restrict__ blksum, int nb) {
  __shared__ int sdata[256];
  const int t = threadIdx.x;
  const int idx = t * 8;
  int v[8];
#pragma unroll
  for (int k = 0; k < 8; ++k) v[k] = (idx + k < nb) ? blksum[idx + k] : 0;
  int tsum = 0;
#pragma unroll
  for (int k = 0; k < 8; ++k) tsum += v[k];
  sdata[t] = tsum;
  __syncthreads();
  for (int off = 1; off < 256; off <<= 1) {
    int x = (t >= off) ? sdata[t - off] : 0;
    __syncthreads();
    sdata[t] += x;
    __syncthreads();
  }
  int run = sdata[t] - tsum;
#pragma unroll
  for (int k = 0; k < 8; ++k) {
    if (idx + k < nb) blksum[idx + k] = run;
    run += v[k];
  }
}

__global__ __launch_bounds__(256)
void scan_add(int* __restrict__ ptr, const int* __restrict__ blkoff, int n) {
  const int off = blkoff[blockIdx.x];
  const int base = blockIdx.x * 1024 + threadIdx.x;
#pragma unroll
  for (int k = 0; k < 4; ++k) {
    int i = base + k * 256;
    if (i < n) ptr[i] += off;
  }
}

// ------------- fused three-matrix two-level counting-sort build ------------
__global__ __launch_bounds__(BT)
void bucket_count3(const int* __restrict__ r0, const int* __restrict__ r1,
                   const int* __restrict__ r2, int* __restrict__ cnt,
                   int nnz0, int nnz1, int nnz2, int nb0, int nb1, int nb2) {
  extern __shared__ int lh[];
  const int m = blockIdx.x / NPASSBLK;
  const int blk = blockIdx.x % NPASSBLK;
  const int tid = threadIdx.x;
  const int* rows = (m == 0) ? r0 : (m == 1) ? r1 : r2;
  const int nnz  = (m == 0) ? nnz0 : (m == 1) ? nnz1 : nnz2;
  const int nbuk = (m == 0) ? nb0 : (m == 1) ? nb1 : nb2;
  const int bukbase = (m == 0) ? 0 : (m == 1) ? nb0 : nb0 + nb1;
  const int chunk = (nnz + NPASSBLK - 1) / NPASSBLK;
  for (int b = tid; b < nbuk; b += BT) lh[b] = 0;
  __syncthreads();
  const int i0 = blk * chunk;
  const int i1 = min(i0 + chunk, nnz);
  for (int i = i0 + tid; i < i1; i += BT) atomicAdd(&lh[rows[i] >> RB_SHIFT], 1);
  __syncthreads();
  for (int b = tid; b < nbuk; b += BT)
    cnt[(size_t)(bukbase + b) * NPASSBLK + blk] = lh[b];
  if (m == 0 && blk == 0 && tid == 0)
    cnt[(size_t)(nb0 + nb1 + nb2) * NPASSBLK] = 0;
}

__global__ __launch_bounds__(BT)
void bucket_scatter3(const int* __restrict__ r0, const int* __restrict__ c0,
                     const float* __restrict__ v0,
                     const int* __restrict__ r1, const int* __restrict__ c1,
                     const float* __restrict__ v1,
                     const int* __restrict__ r2, const int* __restrict__ c2,
                     const float* __restrict__ v2,
                     const int* __restrict__ S, int2* __restrict__ prT,
                     int nnz0, int nnz1, int nnz2, int nb0, int nb1, int nb2) {
  extern __shared__ int lcur[];
  const int m = blockIdx.x / NPASSBLK;
  const int blk = blockIdx.x % NPASSBLK;
  const int tid = threadIdx.x;
  const int* rows = (m == 0) ? r0 : (m == 1) ? r1 : r2;
  const int* cols = (m == 0) ? c0 : (m == 1) ? c1 : c2;
  const float* vals = (m == 0) ? v0 : (m == 1) ? v1 : v2;
  const int nnz  = (m == 0) ? nnz0 : (m == 1) ? nnz1 : nnz2;
  const int nbuk = (m == 0) ? nb0 : (m == 1) ? nb1 : nb2;
  const int bukbase = (m == 0) ? 0 : (m == 1) ? nb0 : nb0 + nb1;
  const int chunk = (nnz + NPASSBLK - 1) / NPASSBLK;
  for (int b = tid; b < nbuk; b += BT)
    lcur[b] = S[(size_t)(bukbase + b) * NPASSBLK + blk];
  __syncthreads();
  const int i0 = blk * chunk;
  const int i1 = min(i0 + chunk, nnz);
  for (int i = i0 + tid; i < i1; i += BT) {
    const int r = rows[i];
    const int p = atomicAdd(&lcur[r >> RB_SHIFT], 1);
    prT[p] = make_int2(cols[i] | ((r & (RB - 1)) << 26), __float_as_int(vals[i]));
  }
}

__global__ __launch_bounds__(256)
void bucket_to_csr3(const int* __restrict__ S, const int2* __restrict__ prT,
                    int2* __restrict__ pA, int* __restrict__ ptA,
                    int2* __restrict__ pE, int* __restrict__ ptE,
                    int2* __restrict__ pI, int* __restrict__ ptI,
                    int nr0, int nr1, int nr2,
                    int nb0, int nb1, int nnz0, int nnz1) {
  __shared__ int h[RB + 1];
  __shared__ int cur[RB];
  const int b = blockIdx.x, tid = threadIdx.x;
  const int m = (b < nb0) ? 0 : (b < nb0 + nb1) ? 1 : 2;
  const int lb = (m == 0) ? b : (m == 1) ? b - nb0 : b - nb0 - nb1;
  const int nnzbase = (m == 0) ? 0 : (m == 1) ? nnz0 : nnz0 + nnz1;
  const int n_rows = (m == 0) ? nr0 : (m == 1) ? nr1 : nr2;
  int2* pr = (m == 0) ? pA : (m == 1) ? pE : pI;
  int* ptr = (m == 0) ? ptA : (m == 1) ? ptE : ptI;

  const int js = S[(size_t)b * NPASSBLK];
  const int je = S[(size_t)(b + 1) * NPASSBLK];
  if (tid <= RB) h[tid] = 0;
  __syncthreads();
  for (int j = js + tid; j < je; j += 256)
    atomicAdd(&h[((unsigned)prT[j].x) >> 26], 1);
  __syncthreads();
  if (tid == 0) {
    int run = js;
    for (int t = 0; t < RB; ++t) { int c = h[t]; h[t] = run; cur[t] = run; run += c; }
    h[RB] = run;   // == je
  }
  __syncthreads();
  if (tid <= RB) {
    const int r = lb * RB + tid;
    if (r <= n_rows) ptr[r] = h[tid] - nnzbase;
  }
  // final pr.x = col * 256 (byte offset of the feature row, CF*2 = 256 B)
  for (int j = js + tid; j < je; j += 256) {
    const int2 e = prT[j];
    const unsigned cw = (unsigned)e.x;
    const int p = atomicAdd(&cur[cw >> 26], 1);
    pr[p - nnzbase] = make_int2((int)((cw & 0x03FFFFFFu) << 8), e.y);
  }
}

// ----------------------------- CSR SpMM (quad-gather) ----------------------
// Wave = 4 groups x 16 lanes; group g handles nnz j+g; lane q loads uint4
// (8 features) at X + p.x + q*16 (p.x = col*256 byte offset).
// Bulk loop (UNR unmasked) -> mid loop (4 nnz, unmasked) -> one masked tail.
__device__ __forceinline__ void fma8(const uint4& d, float v, f32x2* acc) {
  const f32x2 vv = {v, v};
  acc[0] = __builtin_elementwise_fma(vv, bf2v(d.x), acc[0]);
  acc[1] = __builtin_elementwise_fma(vv, bf2v(d.y), acc[1]);
  acc[2] = __builtin_elementwise_fma(vv, bf2v(d.z), acc[2]);
  acc[3] = __builtin_elementwise_fma(vv, bf2v(d.w), acc[3]);
}

template <int UNR>
__device__ __forceinline__ void seg_accum(const int* __restrict__ ptr,
                                          const int2* __restrict__ pr,
                                          const char* __restrict__ Xb,
                                          unsigned qb, int wid, int g,
                                          f32x2* acc) {
  int j = ptr[wid];
  const int je = ptr[wid + 1];
  if (UNR > 1) {
    for (; j + 4 * UNR <= je; j += 4 * UNR) {
      int2 p[UNR];
#pragma unroll
      for (int u = 0; u < UNR; ++u) p[u] = pr[j + 4 * u + g];
      uint4 d[UNR];
#pragma unroll
      for (int u = 0; u < UNR; ++u)
        d[u] = *(const uint4*)(Xb + (unsigned)(p[u].x | (int)qb));
#pragma unroll
      for (int u = 0; u < UNR; ++u) fma8(d[u], __int_as_float(p[u].y), acc);
    }
  }
  for (; j + 4 <= je; j += 4) {
    const int2 p = pr[j + g];
    const uint4 d = *(const uint4*)(Xb + (unsigned)(p.x | (int)qb));
    fma8(d, __int_as_float(p.y), acc);
  }
  if (j < je) {
    const int jj = j + g;
    const int2 p = (jj < je) ? pr[jj] : make_int2(0, 0);
    const uint4 d = *(const uint4*)(Xb + (unsigned)(p.x | (int)qb));
    fma8(d, __int_as_float(p.y), acc);
  }
}

template <bool SIG, int UNR>
__device__ __forceinline__ void spmm_body(const int* __restrict__ ptr,
                                          const int2* __restrict__ pr,
                                          const unsigned* __restrict__ X,
                                          unsigned* __restrict__ Y,
                                          int n_rows, int blk) {
  const int wid = (blk << 2) + (threadIdx.x >> 6);
  if (wid >= n_rows) return;
  const int lane = threadIdx.x & 63;
  const int g = lane >> 4;
  const unsigned qb = (unsigned)(lane & 15) << 4;   // byte offset of lane's uint4
  f32x2 acc[4];
#pragma unroll
  for (int k = 0; k < 4; ++k) acc[k] = (f32x2){0.f, 0.f};
  seg_accum<UNR>(ptr, pr, (const char*)X, qb, wid, g, acc);
#pragma unroll
  for (int k = 0; k < 4; ++k) {
    acc[k].x += __shfl_xor(acc[k].x, 16);
    acc[k].y += __shfl_xor(acc[k].y, 16);
    acc[k].x += __shfl_xor(acc[k].x, 32);
    acc[k].y += __shfl_xor(acc[k].y, 32);
  }
  if (g == 0) {
    if (SIG) {
#pragma unroll
      for (int k = 0; k < 4; ++k) {
        acc[k].x = 1.f / (1.f + __expf(-acc[k].x));
        acc[k].y = 1.f / (1.f + __expf(-acc[k].y));
      }
    }
    uint4 o;
    o.x = (unsigned)bf16rne(acc[0].x) | ((unsigned)bf16rne(acc[0].y) << 16);
    o.y = (unsigned)bf16rne(acc[1].x) | ((unsigned)bf16rne(acc[1].y) << 16);
    o.z = (unsigned)bf16rne(acc[2].x) | ((unsigned)bf16rne(acc[2].y) << 16);
    o.w = (unsigned)bf16rne(acc[3].x) | ((unsigned)bf16rne(acc[3].y) << 16);
    *(uint4*)(Y + (size_t)wid * 64 + (qb >> 2)) = o;
  }
}

// Dual-row wave for short-row CSR (edge side, avg 2 nnz/row): groups {0,1}
// serve row 2w (nnz j+0/j+1, stride 2), groups {2,3} row 2w+1. xor-16 pairs
// g0<->g1 and g2<->g3 complete each row's reduction; g0/g2 write.
__device__ __forceinline__ void seg_accum_dual(const int* __restrict__ ptr,
                                               const int2* __restrict__ pr,
                                               const char* __restrict__ Xb,
                                               unsigned qb, int row, int gg,
                                               f32x2* acc) {
  int j = ptr[row];
  const int je = ptr[row + 1];
  for (; j + 2 <= je; j += 2) {
    const int2 p = pr[j + gg];
    const uint4 d = *(const uint4*)(Xb + (unsigned)(p.x | (int)qb));
    fma8(d, __int_as_float(p.y), acc);
  }
  if (j < je) {
    const int jj = j + gg;
    const int2 p = (jj < je) ? pr[jj] : make_int2(0, 0);
    const uint4 d = *(const uint4*)(Xb + (unsigned)(p.x | (int)qb));
    fma8(d, __int_as_float(p.y), acc);
  }
}

__device__ __forceinline__ void spmm_dual_body(const int* __restrict__ ptr,
                                               const int2* __restrict__ pr,
                                               const unsigned* __restrict__ X,
                                               unsigned* __restrict__ Y,
                                               int n_rows, int blk) {
  const int wpair = (blk << 2) + (threadIdx.x >> 6);
  const int row0 = wpair << 1;
  if (row0 >= n_rows) return;
  const int lane = threadIdx.x & 63;
  const int g = lane >> 4;
  const int gg = g & 1;
  const int row = row0 + (g >> 1);
  const unsigned qb = (unsigned)(lane & 15) << 4;
  f32x2 acc[4];
#pragma unroll
  for (int k = 0; k < 4; ++k) acc[k] = (f32x2){0.f, 0.f};
  const bool live = (row < n_rows);
  if (live) seg_accum_dual(ptr, pr, (const char*)X, qb, row, gg, acc);
#pragma unroll
  for (int k = 0; k < 4; ++k) {
    acc[k].x += __shfl_xor(acc[k].x, 16);
    acc[k].y += __shfl_xor(acc[k].y, 16);
  }
  if (gg == 0 && live) {
#pragma unroll
    for (int k = 0; k < 4; ++k) {
      acc[k].x = 1.f / (1.f + __expf(-acc[k].x));
      acc[k].y = 1.f / (1.f + __expf(-acc[k].y));
    }
    uint4 o;
    o.x = (unsigned)bf16rne(acc[0].x) | ((unsigned)bf16rne(acc[0].y) << 16);
    o.y = (unsigned)bf16rne(acc[1].x) | ((unsigned)bf16rne(acc[1].y) << 16);
    o.z = (unsigned)bf16rne(acc[2].x) | ((unsigned)bf16rne(acc[2].y) << 16);
    o.w = (unsigned)bf16rne(acc[3].x) | ((unsigned)bf16rne(acc[3].y) << 16);
    *(uint4*)(Y + (size_t)row * 64 + (qb >> 2)) = o;
  }
}

// fused level-1 SpMMs: blocks [0,split) adj->n1 (UNR8), rest incT->e1 (dual-row)
__global__ __launch_bounds__(256)
void csr_spmm_l1(const int* __restrict__ ptrA, const int2* __restrict__ prA,
                 const unsigned* __restrict__ XA, unsigned* __restrict__ YA, int nA,
                 const int* __restrict__ ptrE, const int2* __restrict__ prE,
                 const unsigned* __restrict__ XE, unsigned* __restrict__ YE, int nE,
                 int split) {
  if ((int)blockIdx.x < split)
    spmm_body<true, 8>(ptrA, prA, XA, YA, nA, blockIdx.x);
  else
    spmm_dual_body(ptrE, prE, XE, YE, nE, blockIdx.x - split);
}

// Fused level-2 merge: out[r] = sigmoid( adj-seg(XA) + inc-seg(XB) ), f32 out.
__global__ __launch_bounds__(256)
void csr_spmm2_sig(const int* __restrict__ ptrA, const int2* __restrict__ prA,
                   const unsigned* __restrict__ XA,
                   const int* __restrict__ ptrB, const int2* __restrict__ prB,
                   const unsigned* __restrict__ XB,
                   float* __restrict__ Y, int n_rows) {
  const int wid = (blockIdx.x << 2) + (threadIdx.x >> 6);
  if (wid >= n_rows) return;
  const int lane = threadIdx.x & 63;
  const int g = lane >> 4;
  const unsigned qb = (unsigned)(lane & 15) << 4;
  f32x2 acc[4];
#pragma unroll
  for (int k = 0; k < 4; ++k) acc[k] = (f32x2){0.f, 0.f};
  seg_accum<8>(ptrA, prA, (const char*)XA, qb, wid, g, acc);
  seg_accum<1>(ptrB, prB, (const char*)XB, qb, wid, g, acc);
#pragma unroll
  for (int k = 0; k < 4; ++k) {
    acc[k].x += __shfl_xor(acc[k].x, 16);
    acc[k].y += __shfl_xor(acc[k].y, 16);
    acc[k].x += __shfl_xor(acc[k].x, 32);
    acc[k].y += __shfl_xor(acc[k].y, 32);
  }
  if (g == 0) {
#pragma unroll
    for (int k = 0; k < 4; ++k) {
      acc[k].x = 1.f / (1.f + __expf(-acc[k].x));
      acc[k].y = 1.f / (1.f + __expf(-acc[k].y));
    }
    float4* yp = (float4*)(Y + (size_t)wid * CF + (qb >> 1));
    yp[0] = make_float4(acc[0].x, acc[0].y, acc[1].x, acc[1].y);
    yp[1] = make_float4(acc[2].x, acc[2].y, acc[3].x, acc[3].y);
  }
}

// ---------------------------------------------------------------------------
extern "C" void kernel_launch(void* const* d_in, const int* in_sizes, int n_in,
                              void* d_out, int out_size, void* d_ws, size_t ws_size,
                              hipStream_t stream) {
  const float* x      = (const float*)d_in[0];
  const float* W1_00  = (const float*)d_in[1];
  const float* W1_01  = (const float*)d_in[2];
  const float* W2_00  = (const float*)d_in[3];
  const float* W2_10  = (const float*)d_in[4];
  const int*   adj_rows = (const int*)d_in[5];
  const int*   adj_cols = (const int*)d_in[6];
  const float* adj_vals = (const float*)d_in[7];
  const int*   inc_rows = (const int*)d_in[8];
  const int*   inc_cols = (const int*)d_in[9];
  const float* inc_vals = (const float*)d_in[10];

  const int adj_nnz = in_sizes[5];       // 3,200,000
  const int inc_nnz = in_sizes[8];       // 400,000
  const int NN = in_sizes[0] / CF;       // 100,000 nodes
  const int EN = 200000;                 // edges (problem constant)

  const long long NE = (long long)NN * CF;   // node features
  const long long EE = (long long)EN * CF;   // edge features
  const int PN = ((NN + 2) & ~1);            // padded (8B-align int2 arrays)
  const int PE = ((EN + 2) & ~1);

  // ---- workspace layout ----
  unsigned short* tA = (unsigned short*)d_ws;   // NE bf16 ; prT alias at build
  unsigned short* n1 = tA + NE;                 // NE bf16 ; prT spill region
  unsigned short* e1 = n1 + NE;                 // EE bf16 ; cnt/S alias at build
  int*   ptr_a = (int*)(e1 + EE);
  int*   cur_a = ptr_a + PN;                    // (unused, layout stability)
  int2*  pr_a  = (int2*)(cur_a + PN);
  int*   ptr_e = (int*)(pr_a + adj_nnz);
  int*   cur_e = ptr_e + PE;                    // (unused)
  int2*  pr_e  = (int2*)(cur_e + PE);
  int*   ptr_i = (int*)(pr_e + inc_nnz);
  int*   cur_i = ptr_i + PN;                    // (unused)
  int2*  pr_i  = (int2*)(cur_i + PN);
  int*   blks  = (int*)(pr_i + inc_nnz);        // 2048 ints
  short* wp = (short*)(((uintptr_t)(blks + 2048) + 63) & ~(uintptr_t)63);
  short* w00 = wp;             // hi at +0, lo at +16384
  short* w01 = wp + 2 * 16384;
  short* w20 = wp + 4 * 16384;
  short* w21 = wp + 6 * 16384;

  // build-time scratch aliased onto feature buffers (dead until GEMMs/SpMMs):
  int2* prT  = (int2*)tA;
  int*  cntA = (int*)e1;
  int*  SA   = cntA + 1600512;

  unsigned short* t1 = (unsigned short*)d_out;  // bf16 scratch; dead before final write
  float* outf = (float*)d_out;

  const dim3 blk(256);
  const int gN = (NN + 63) / 64;                // 1563
  const int gE = (EN + 63) / 64;                // 3125
  const int nbukN = (NN + RB - 1) >> RB_SHIFT;  // 1563
  const int nbukE = (EN + RB - 1) >> RB_SHIFT;  // 3125
  const int totbuk = nbukN + nbukE + nbukN;     // 6251
  const int nS = totbuk * NPASSBLK + 1;         // 1,600,257
  const int nbS = (nS + 1023) / 1024;           // 1563 (<= 2048 scan_sums cap)
  const int ldsbk = nbukE * 4;                  // max bucket count LDS bytes

  // ---- pack weights (1) ----
  pack_w4<<<32, blk, 0, stream>>>(W1_00, W1_01, W2_00, W2_10, wp);

  // ---- fused CSR builds (2-7): count3, scan x3, scatter3, to_csr3 ----
  bucket_count3<<<3 * NPASSBLK, dim3(BT), ldsbk, stream>>>(
      adj_rows, inc_cols, inc_rows, cntA,
      adj_nnz, inc_nnz, inc_nnz, nbukN, nbukE, nbukN);
  scan_block<<<nbS, blk, 0, stream>>>(cntA, SA, blks, nS);
  scan_sums<<<1, blk, 0, stream>>>(blks, nbS);
  scan_add<<<nbS, blk, 0, stream>>>(SA, blks, nS);
  bucket_scatter3<<<3 * NPASSBLK, dim3(BT), ldsbk, stream>>>(
      adj_rows, adj_cols, adj_vals,
      inc_cols, inc_rows, inc_vals,
      inc_rows, inc_cols, inc_vals,
      SA, prT, adj_nnz, inc_nnz, inc_nnz, nbukN, nbukE, nbukN);
  bucket_to_csr3<<<totbuk, blk, 0, stream>>>(
      SA, prT, pr_a, ptr_a, pr_e, ptr_e, pr_i, ptr_i,
      NN, EN, NN, nbukN, nbukE, adj_nnz, inc_nnz);

  // ---- level 1 GEMMs fused (8): t1 = x@W1_00, tA = x@W1_01 ----
  gemm_f32_l1<<<2 * gN, dim3(128), 0, stream>>>(x, w00, w01, t1, tA, NN, gN);

  // ---- level 1 SpMMs fused (9): n1 = sig(adj-seg t1), e1 = sig(incT-seg tA) --
  const int spN = (NN + 3) / 4;
  const int spE2 = (((EN + 1) / 2) + 3) / 4;    // dual-row: 2 rows per wave
  csr_spmm_l1<<<spN + spE2, blk, 0, stream>>>(
      ptr_a, pr_a, (const unsigned*)t1, (unsigned*)n1, NN,
      ptr_e, pr_e, (const unsigned*)tA, (unsigned*)e1, EN, spN);

  // ---- level 2 GEMMs fused (10): n1 = n1@W2_00, e1 = e1@W2_10 (in-place) ----
  gemm_b16_l2<<<gN + gE, dim3(128), 0, stream>>>(
      (unsigned short*)n1, w20, (unsigned short*)e1, w21, NN, EN, gN);

  // ---- fused level-2 SpMMs + merge sigmoid (11) ----
  csr_spmm2_sig<<<spN, blk, 0, stream>>>(ptr_a, pr_a, (const unsigned*)n1,
                                         ptr_i, pr_i, (const unsigned*)e1, outf, NN);
}

// Round 8
// 621.266 us; speedup vs baseline: 1.1428x; 1.1428x over previous
//
#include <hip/hip_runtime.h>

// HSN layer: out = sigmoid( A0 @ (sig(A0 @ (x W1_00)) W2_00) + B1 @ (sig(B1^T @ (x W1_01)) W2_10) )
// C = 128 fixed. CSR-gather SpMM (no f32 atomics) + MFMA GEMMs.
// Intermediate features bf16. CSR build: fused 3-matrix two-level LDS counting
// sort. 11 dispatches total.
// R8: revert UNR8 (2nd confirmed VGPR/occupancy loss: 48 VGPR -> 46% occ).
//   Adj segments UNR=4 (28 VGPR, 82% occ). Edge-side incT SpMM (avg 2 nnz/row)
//   -> quad-row waves: each 16-lane group owns a full row (16 x uint4 = 128
//   features), serial over its nnz, no shuffle, 4 rows/wave.

#define CF 128
#define RB 64          // rows per bucket (2^RB_SHIFT)
#define RB_SHIFT 6
#define NPASSBLK 256   // blocks (chunks) per matrix in count/scatter passes
#define BT 512         // threads per count/scatter block

typedef __attribute__((ext_vector_type(8))) short bf16x8;
typedef __attribute__((ext_vector_type(4))) float f32x4;
typedef __attribute__((ext_vector_type(2))) float f32x2;

__device__ __forceinline__ unsigned short bf16rne(float f) {
  unsigned u = __float_as_uint(f);
  u += 0x7FFFu + ((u >> 16) & 1u);
  return (unsigned short)(u >> 16);
}
__device__ __forceinline__ void splitf(float f, short& h, short& l) {
  unsigned u = __float_as_uint(f);
  h = (short)(u >> 16);
  float fh = __uint_as_float(u & 0xFFFF0000u);
  float r = f - fh;
  l = (short)(__float_as_uint(r) >> 16);
}
__device__ __forceinline__ f32x2 bf2v(unsigned u) {
  f32x2 f;
  f.x = __uint_as_float(u << 16);
  f.y = __uint_as_float(u & 0xFFFF0000u);
  return f;
}

// ---------------------------------------------------------------------------
// Pack 4x W[128][128] f32 into mfma_f32_16x16x32_bf16 B-fragment order:
// frag[(s*8+t)*64+lane][j] = W[s*32+(lane>>4)*8+j][t*16+(lane&15)]
// ---------------------------------------------------------------------------
__global__ __launch_bounds__(256)
void pack_w4(const float* __restrict__ W0, const float* __restrict__ W1,
             const float* __restrict__ W2, const float* __restrict__ W3,
             short* __restrict__ wp) {
  const int w = blockIdx.x >> 3;
  const float* W = (w == 0) ? W0 : (w == 1) ? W1 : (w == 2) ? W2 : W3;
  short* hi = wp + (size_t)w * 32768;
  short* lo = hi + 16384;
  const int tid = (blockIdx.x & 7) * 256 + threadIdx.x;   // 0..2047
  const int lane = tid & 63;
  const int t = (tid >> 6) & 7;
  const int s = tid >> 9;
  const int n = t * 16 + (lane & 15);
  const int k0 = s * 32 + ((lane >> 4) << 3);
  short* hp = hi + (size_t)tid * 8;
  short* lp = lo + (size_t)tid * 8;
#pragma unroll
  for (int j = 0; j < 8; ++j) {
    short h, l;
    splitf(W[(size_t)(k0 + j) * CF + n], h, l);
    hp[j] = h;
    lp[j] = l;
  }
}

// ---------------------------------------------------------------------------
// GEMM bodies (device functions, called from fused range-dispatch kernels)
// ---------------------------------------------------------------------------
__device__ __forceinline__ void gemm_f32_body(const float* __restrict__ X,
                                              const short* __restrict__ Whi,
                                              const short* __restrict__ Wlo,
                                              unsigned short* __restrict__ Y,
                                              int M, int blk) {
  const int wave = threadIdx.x >> 6;
  const int lane = threadIdx.x & 63;
  const int mrow = lane & 15;
  const int quad = lane >> 4;
  const int row0 = blk * 64 + wave * 32;

  const bf16x8* WH = (const bf16x8*)Whi;
  const bf16x8* WL = (const bf16x8*)Wlo;

  f32x4 acc[2][8];
#pragma unroll
  for (int mt = 0; mt < 2; ++mt)
#pragma unroll
    for (int t = 0; t < 8; ++t) acc[mt][t] = (f32x4){0.f, 0.f, 0.f, 0.f};

  int rA0 = row0 + mrow;      if (rA0 > M - 1) rA0 = M - 1;
  int rA1 = row0 + 16 + mrow; if (rA1 > M - 1) rA1 = M - 1;
  const float* xp0 = X + (size_t)rA0 * CF + quad * 8;
  const float* xp1 = X + (size_t)rA1 * CF + quad * 8;

#pragma unroll
  for (int s = 0; s < 4; ++s) {
    bf16x8 Ah[2], Al[2];
    const float* p = xp0 + s * 32;
#pragma unroll
    for (int j = 0; j < 8; ++j) { short h, l; splitf(p[j], h, l); Ah[0][j] = h; Al[0][j] = l; }
    p = xp1 + s * 32;
#pragma unroll
    for (int j = 0; j < 8; ++j) { short h, l; splitf(p[j], h, l); Ah[1][j] = h; Al[1][j] = l; }
#pragma unroll
    for (int t = 0; t < 8; ++t) {
      const bf16x8 bh = WH[(s * 8 + t) * 64 + lane];
      const bf16x8 bl = WL[(s * 8 + t) * 64 + lane];
#pragma unroll
      for (int mt = 0; mt < 2; ++mt) {
        acc[mt][t] = __builtin_amdgcn_mfma_f32_16x16x32_bf16(Ah[mt], bh, acc[mt][t], 0, 0, 0);
        acc[mt][t] = __builtin_amdgcn_mfma_f32_16x16x32_bf16(Al[mt], bh, acc[mt][t], 0, 0, 0);
        acc[mt][t] = __builtin_amdgcn_mfma_f32_16x16x32_bf16(Ah[mt], bl, acc[mt][t], 0, 0, 0);
      }
    }
  }

#pragma unroll
  for (int mt = 0; mt < 2; ++mt)
#pragma unroll
    for (int reg = 0; reg < 4; ++reg) {
      const int r = row0 + mt * 16 + quad * 4 + reg;
      if (r < M) {
        unsigned short* yp = Y + (size_t)r * CF + mrow;
#pragma unroll
        for (int t = 0; t < 8; ++t) yp[t * 16] = bf16rne(acc[mt][t][reg]);
      }
    }
}

__device__ __forceinline__ void gemm_b16_body(const unsigned short* __restrict__ X,
                                              const short* __restrict__ Whi,
                                              const short* __restrict__ Wlo,
                                              unsigned short* __restrict__ Y,
                                              int M, int blk) {
  const int wave = threadIdx.x >> 6;
  const int lane = threadIdx.x & 63;
  const int mrow = lane & 15;
  const int quad = lane >> 4;
  const int row0 = blk * 64 + wave * 32;

  const bf16x8* WH = (const bf16x8*)Whi;
  const bf16x8* WL = (const bf16x8*)Wlo;

  f32x4 acc[2][8];
#pragma unroll
  for (int mt = 0; mt < 2; ++mt)
#pragma unroll
    for (int t = 0; t < 8; ++t) acc[mt][t] = (f32x4){0.f, 0.f, 0.f, 0.f};

  int rA0 = row0 + mrow;      if (rA0 > M - 1) rA0 = M - 1;
  int rA1 = row0 + 16 + mrow; if (rA1 > M - 1) rA1 = M - 1;
  const bf16x8* xp0 = (const bf16x8*)(X + (size_t)rA0 * CF + quad * 8);
  const bf16x8* xp1 = (const bf16x8*)(X + (size_t)rA1 * CF + quad * 8);

#pragma unroll
  for (int s = 0; s < 4; ++s) {
    bf16x8 A0 = xp0[s * 4];
    bf16x8 A1 = xp1[s * 4];
#pragma unroll
    for (int t = 0; t < 8; ++t) {
      const bf16x8 bh = WH[(s * 8 + t) * 64 + lane];
      const bf16x8 bl = WL[(s * 8 + t) * 64 + lane];
      acc[0][t] = __builtin_amdgcn_mfma_f32_16x16x32_bf16(A0, bh, acc[0][t], 0, 0, 0);
      acc[0][t] = __builtin_amdgcn_mfma_f32_16x16x32_bf16(A0, bl, acc[0][t], 0, 0, 0);
      acc[1][t] = __builtin_amdgcn_mfma_f32_16x16x32_bf16(A1, bh, acc[1][t], 0, 0, 0);
      acc[1][t] = __builtin_amdgcn_mfma_f32_16x16x32_bf16(A1, bl, acc[1][t], 0, 0, 0);
    }
  }

#pragma unroll
  for (int mt = 0; mt < 2; ++mt)
#pragma unroll
    for (int reg = 0; reg < 4; ++reg) {
      const int r = row0 + mt * 16 + quad * 4 + reg;
      if (r < M) {
        unsigned short* yp = Y + (size_t)r * CF + mrow;
#pragma unroll
        for (int t = 0; t < 8; ++t) yp[t * 16] = bf16rne(acc[mt][t][reg]);
      }
    }
}

// fused L1: blocks [0,g) -> Y0 = X@W00 ; [g,2g) -> Y1 = X@W01 (same X, M)
__global__ __launch_bounds__(128)
void gemm_f32_l1(const float* __restrict__ X,
                 const short* __restrict__ w00, const short* __restrict__ w01,
                 unsigned short* __restrict__ Y0, unsigned short* __restrict__ Y1,
                 int M, int g) {
  if ((int)blockIdx.x < g)
    gemm_f32_body(X, w00, w00 + 16384, Y0, M, blockIdx.x);
  else
    gemm_f32_body(X, w01, w01 + 16384, Y1, M, blockIdx.x - g);
}

// fused L2: blocks [0,gN) -> n1 = n1@W20 ; [gN,gN+gE) -> e1 = e1@W21
__global__ __launch_bounds__(128)
void gemm_b16_l2(unsigned short* __restrict__ n1, const short* __restrict__ w20,
                 unsigned short* __restrict__ e1, const short* __restrict__ w21,
                 int MN, int ME, int gN) {
  if ((int)blockIdx.x < gN)
    gemm_b16_body(n1, w20, w20 + 16384, n1, MN, blockIdx.x);
  else
    gemm_b16_body(e1, w21, w21 + 16384, e1, ME, blockIdx.x - gN);
}

// --------------------------- scan kernels ----------------------------------
__global__ __launch_bounds__(256)
void scan_block(const int* __restrict__ cnt, int* __restrict__ ptr,
                int* __restrict__ blksum, int n) {
  __shared__ int sdata[256];
  const int t = threadIdx.x;
  const int idx = blockIdx.x * 1024 + t * 4;
  int v[4];
#pragma unroll
  for (int k = 0; k < 4; ++k) v[k] = (idx + k < n) ? cnt[idx + k] : 0;
  int tsum = v[0] + v[1] + v[2] + v[3];
  sdata[t] = tsum;
  __syncthreads();
  for (int off = 1; off < 256; off <<= 1) {
    int x = (t >= off) ? sdata[t - off] : 0;
    __syncthreads();
    sdata[t] += x;
    __syncthreads();
  }
  if (t == 255) blksum[blockIdx.x] = sdata[255];
  int run = sdata[t] - tsum;
#pragma unroll
  for (int k = 0; k < 4; ++k) {
    if (idx + k < n) ptr[idx + k] = run;
    run += v[k];
  }
}

// exclusive scan of up to 2048 block sums, one 256-thread block.
__global__ __launch_bounds__(256)
void scan_sums(int* __restrict__ blksum, int nb) {
  __shared__ int sdata[256];
  const int t = threadIdx.x;
  const int idx = t * 8;
  int v[8];
#pragma unroll
  for (int k = 0; k < 8; ++k) v[k] = (idx + k < nb) ? blksum[idx + k] : 0;
  int tsum = 0;
#pragma unroll
  for (int k = 0; k < 8; ++k) tsum += v[k];
  sdata[t] = tsum;
  __syncthreads();
  for (int off = 1; off < 256; off <<= 1) {
    int x = (t >= off) ? sdata[t - off] : 0;
    __syncthreads();
    sdata[t] += x;
    __syncthreads();
  }
  int run = sdata[t] - tsum;
#pragma unroll
  for (int k = 0; k < 8; ++k) {
    if (idx + k < nb) blksum[idx + k] = run;
    run += v[k];
  }
}

__global__ __launch_bounds__(256)
void scan_add(int* __restrict__ ptr, const int* __restrict__ blkoff, int n) {
  const int off = blkoff[blockIdx.x];
  const int base = blockIdx.x * 1024 + threadIdx.x;
#pragma unroll
  for (int k = 0; k < 4; ++k) {
    int i = base + k * 256;
    if (i < n) ptr[i] += off;
  }
}

// ------------- fused three-matrix two-level counting-sort build ------------
__global__ __launch_bounds__(BT)
void bucket_count3(const int* __restrict__ r0, const int* __restrict__ r1,
                   const int* __restrict__ r2, int* __restrict__ cnt,
                   int nnz0, int nnz1, int nnz2, int nb0, int nb1, int nb2) {
  extern __shared__ int lh[];
  const int m = blockIdx.x / NPASSBLK;
  const int blk = blockIdx.x % NPASSBLK;
  const int tid = threadIdx.x;
  const int* rows = (m == 0) ? r0 : (m == 1) ? r1 : r2;
  const int nnz  = (m == 0) ? nnz0 : (m == 1) ? nnz1 : nnz2;
  const int nbuk = (m == 0) ? nb0 : (m == 1) ? nb1 : nb2;
  const int bukbase = (m == 0) ? 0 : (m == 1) ? nb0 : nb0 + nb1;
  const int chunk = (nnz + NPASSBLK - 1) / NPASSBLK;
  for (int b = tid; b < nbuk; b += BT) lh[b] = 0;
  __syncthreads();
  const int i0 = blk * chunk;
  const int i1 = min(i0 + chunk, nnz);
  for (int i = i0 + tid; i < i1; i += BT) atomicAdd(&lh[rows[i] >> RB_SHIFT], 1);
  __syncthreads();
  for (int b = tid; b < nbuk; b += BT)
    cnt[(size_t)(bukbase + b) * NPASSBLK + blk] = lh[b];
  if (m == 0 && blk == 0 && tid == 0)
    cnt[(size_t)(nb0 + nb1 + nb2) * NPASSBLK] = 0;
}

__global__ __launch_bounds__(BT)
void bucket_scatter3(const int* __restrict__ r0, const int* __restrict__ c0,
                     const float* __restrict__ v0,
                     const int* __restrict__ r1, const int* __restrict__ c1,
                     const float* __restrict__ v1,
                     const int* __restrict__ r2, const int* __restrict__ c2,
                     const float* __restrict__ v2,
                     const int* __restrict__ S, int2* __restrict__ prT,
                     int nnz0, int nnz1, int nnz2, int nb0, int nb1, int nb2) {
  extern __shared__ int lcur[];
  const int m = blockIdx.x / NPASSBLK;
  const int blk = blockIdx.x % NPASSBLK;
  const int tid = threadIdx.x;
  const int* rows = (m == 0) ? r0 : (m == 1) ? r1 : r2;
  const int* cols = (m == 0) ? c0 : (m == 1) ? c1 : c2;
  const float* vals = (m == 0) ? v0 : (m == 1) ? v1 : v2;
  const int nnz  = (m == 0) ? nnz0 : (m == 1) ? nnz1 : nnz2;
  const int nbuk = (m == 0) ? nb0 : (m == 1) ? nb1 : nb2;
  const int bukbase = (m == 0) ? 0 : (m == 1) ? nb0 : nb0 + nb1;
  const int chunk = (nnz + NPASSBLK - 1) / NPASSBLK;
  for (int b = tid; b < nbuk; b += BT)
    lcur[b] = S[(size_t)(bukbase + b) * NPASSBLK + blk];
  __syncthreads();
  const int i0 = blk * chunk;
  const int i1 = min(i0 + chunk, nnz);
  for (int i = i0 + tid; i < i1; i += BT) {
    const int r = rows[i];
    const int p = atomicAdd(&lcur[r >> RB_SHIFT], 1);
    prT[p] = make_int2(cols[i] | ((r & (RB - 1)) << 26), __float_as_int(vals[i]));
  }
}

__global__ __launch_bounds__(256)
void bucket_to_csr3(const int* __restrict__ S, const int2* __restrict__ prT,
                    int2* __restrict__ pA, int* __restrict__ ptA,
                    int2* __restrict__ pE, int* __restrict__ ptE,
                    int2* __restrict__ pI, int* __restrict__ ptI,
                    int nr0, int nr1, int nr2,
                    int nb0, int nb1, int nnz0, int nnz1) {
  __shared__ int h[RB + 1];
  __shared__ int cur[RB];
  const int b = blockIdx.x, tid = threadIdx.x;
  const int m = (b < nb0) ? 0 : (b < nb0 + nb1) ? 1 : 2;
  const int lb = (m == 0) ? b : (m == 1) ? b - nb0 : b - nb0 - nb1;
  const int nnzbase = (m == 0) ? 0 : (m == 1) ? nnz0 : nnz0 + nnz1;
  const int n_rows = (m == 0) ? nr0 : (m == 1) ? nr1 : nr2;
  int2* pr = (m == 0) ? pA : (m == 1) ? pE : pI;
  int* ptr = (m == 0) ? ptA : (m == 1) ? ptE : ptI;

  const int js = S[(size_t)b * NPASSBLK];
  const int je = S[(size_t)(b + 1) * NPASSBLK];
  if (tid <= RB) h[tid] = 0;
  __syncthreads();
  for (int j = js + tid; j < je; j += 256)
    atomicAdd(&h[((unsigned)prT[j].x) >> 26], 1);
  __syncthreads();
  if (tid == 0) {
    int run = js;
    for (int t = 0; t < RB; ++t) { int c = h[t]; h[t] = run; cur[t] = run; run += c; }
    h[RB] = run;   // == je
  }
  __syncthreads();
  if (tid <= RB) {
    const int r = lb * RB + tid;
    if (r <= n_rows) ptr[r] = h[tid] - nnzbase;
  }
  // final pr.x = col * 256 (byte offset of the feature row, CF*2 = 256 B)
  for (int j = js + tid; j < je; j += 256) {
    const int2 e = prT[j];
    const unsigned cw = (unsigned)e.x;
    const int p = atomicAdd(&cur[cw >> 26], 1);
    pr[p - nnzbase] = make_int2((int)((cw & 0x03FFFFFFu) << 8), e.y);
  }
}

// ----------------------------- CSR SpMM (quad-gather) ----------------------
// Wave = 4 groups x 16 lanes; group g handles nnz j+g; lane q loads uint4
// (8 features) at X + p.x + q*16 (p.x = col*256 byte offset).
// Bulk loop (UNR unmasked) -> mid loop (4 nnz, unmasked) -> one masked tail.
__device__ __forceinline__ void fma8(const uint4& d, float v, f32x2* acc) {
  const f32x2 vv = {v, v};
  acc[0] = __builtin_elementwise_fma(vv, bf2v(d.x), acc[0]);
  acc[1] = __builtin_elementwise_fma(vv, bf2v(d.y), acc[1]);
  acc[2] = __builtin_elementwise_fma(vv, bf2v(d.z), acc[2]);
  acc[3] = __builtin_elementwise_fma(vv, bf2v(d.w), acc[3]);
}

template <int UNR>
__device__ __forceinline__ void seg_accum(const int* __restrict__ ptr,
                                          const int2* __restrict__ pr,
                                          const char* __restrict__ Xb,
                                          unsigned qb, int wid, int g,
                                          f32x2* acc) {
  int j = ptr[wid];
  const int je = ptr[wid + 1];
  if (UNR > 1) {
    for (; j + 4 * UNR <= je; j += 4 * UNR) {
      int2 p[UNR];
#pragma unroll
      for (int u = 0; u < UNR; ++u) p[u] = pr[j + 4 * u + g];
      uint4 d[UNR];
#pragma unroll
      for (int u = 0; u < UNR; ++u)
        d[u] = *(const uint4*)(Xb + (unsigned)(p[u].x | (int)qb));
#pragma unroll
      for (int u = 0; u < UNR; ++u) fma8(d[u], __int_as_float(p[u].y), acc);
    }
  }
  for (; j + 4 <= je; j += 4) {
    const int2 p = pr[j + g];
    const uint4 d = *(const uint4*)(Xb + (unsigned)(p.x | (int)qb));
    fma8(d, __int_as_float(p.y), acc);
  }
  if (j < je) {
    const int jj = j + g;
    const int2 p = (jj < je) ? pr[jj] : make_int2(0, 0);
    const uint4 d = *(const uint4*)(Xb + (unsigned)(p.x | (int)qb));
    fma8(d, __int_as_float(p.y), acc);
  }
}

template <bool SIG, int UNR>
__device__ __forceinline__ void spmm_body(const int* __restrict__ ptr,
                                          const int2* __restrict__ pr,
                                          const unsigned* __restrict__ X,
                                          unsigned* __restrict__ Y,
                                          int n_rows, int blk) {
  const int wid = (blk << 2) + (threadIdx.x >> 6);
  if (wid >= n_rows) return;
  const int lane = threadIdx.x & 63;
  const int g = lane >> 4;
  const unsigned qb = (unsigned)(lane & 15) << 4;   // byte offset of lane's uint4
  f32x2 acc[4];
#pragma unroll
  for (int k = 0; k < 4; ++k) acc[k] = (f32x2){0.f, 0.f};
  seg_accum<UNR>(ptr, pr, (const char*)X, qb, wid, g, acc);
#pragma unroll
  for (int k = 0; k < 4; ++k) {
    acc[k].x += __shfl_xor(acc[k].x, 16);
    acc[k].y += __shfl_xor(acc[k].y, 16);
    acc[k].x += __shfl_xor(acc[k].x, 32);
    acc[k].y += __shfl_xor(acc[k].y, 32);
  }
  if (g == 0) {
    if (SIG) {
#pragma unroll
      for (int k = 0; k < 4; ++k) {
        acc[k].x = 1.f / (1.f + __expf(-acc[k].x));
        acc[k].y = 1.f / (1.f + __expf(-acc[k].y));
      }
    }
    uint4 o;
    o.x = (unsigned)bf16rne(acc[0].x) | ((unsigned)bf16rne(acc[0].y) << 16);
    o.y = (unsigned)bf16rne(acc[1].x) | ((unsigned)bf16rne(acc[1].y) << 16);
    o.z = (unsigned)bf16rne(acc[2].x) | ((unsigned)bf16rne(acc[2].y) << 16);
    o.w = (unsigned)bf16rne(acc[3].x) | ((unsigned)bf16rne(acc[3].y) << 16);
    *(uint4*)(Y + (size_t)wid * 64 + (qb >> 2)) = o;
  }
}

// Quad-row wave for short-row CSR (edge side, avg 2 nnz/row): each 16-lane
// group owns a full row (16 x uint4 covers all 128 features), serial over its
// nnz -- no shuffle, no idle groups, 4 rows per wave.
__device__ __forceinline__ void spmm_quad_body(const int* __restrict__ ptr,
                                               const int2* __restrict__ pr,
                                               const unsigned* __restrict__ X,
                                               unsigned* __restrict__ Y,
                                               int n_rows, int blk) {
  const int wid = (blk << 2) + (threadIdx.x >> 6);
  const int lane = threadIdx.x & 63;
  const int g = lane >> 4;
  const int row = (wid << 2) + g;
  if (row >= n_rows) return;
  const unsigned qb = (unsigned)(lane & 15) << 4;
  const char* Xb = (const char*)X;
  f32x2 acc[4];
#pragma unroll
  for (int k = 0; k < 4; ++k) acc[k] = (f32x2){0.f, 0.f};
  int j = ptr[row];
  const int je = ptr[row + 1];
  for (; j < je; ++j) {
    const int2 p = pr[j];
    const uint4 d = *(const uint4*)(Xb + (unsigned)(p.x | (int)qb));
    fma8(d, __int_as_float(p.y), acc);
  }
#pragma unroll
  for (int k = 0; k < 4; ++k) {
    acc[k].x = 1.f / (1.f + __expf(-acc[k].x));
    acc[k].y = 1.f / (1.f + __expf(-acc[k].y));
  }
  uint4 o;
  o.x = (unsigned)bf16rne(acc[0].x) | ((unsigned)bf16rne(acc[0].y) << 16);
  o.y = (unsigned)bf16rne(acc[1].x) | ((unsigned)bf16rne(acc[1].y) << 16);
  o.z = (unsigned)bf16rne(acc[2].x) | ((unsigned)bf16rne(acc[2].y) << 16);
  o.w = (unsigned)bf16rne(acc[3].x) | ((unsigned)bf16rne(acc[3].y) << 16);
  *(uint4*)(Y + (size_t)row * 64 + (qb >> 2)) = o;
}

// fused level-1 SpMMs: blocks [0,split) adj->n1 (UNR4), rest incT->e1 (quad-row)
__global__ __launch_bounds__(256)
void csr_spmm_l1(const int* __restrict__ ptrA, const int2* __restrict__ prA,
                 const unsigned* __restrict__ XA, unsigned* __restrict__ YA, int nA,
                 const int* __restrict__ ptrE, const int2* __restrict__ prE,
                 const unsigned* __restrict__ XE, unsigned* __restrict__ YE, int nE,
                 int split) {
  if ((int)blockIdx.x < split)
    spmm_body<true, 4>(ptrA, prA, XA, YA, nA, blockIdx.x);
  else
    spmm_quad_body(ptrE, prE, XE, YE, nE, blockIdx.x - split);
}

// Fused level-2 merge: out[r] = sigmoid( adj-seg(XA) + inc-seg(XB) ), f32 out.
__global__ __launch_bounds__(256)
void csr_spmm2_sig(const int* __restrict__ ptrA, const int2* __restrict__ prA,
                   const unsigned* __restrict__ XA,
                   const int* __restrict__ ptrB, const int2* __restrict__ prB,
                   const unsigned* __restrict__ XB,
                   float* __restrict__ Y, int n_rows) {
  const int wid = (blockIdx.x << 2) + (threadIdx.x >> 6);
  if (wid >= n_rows) return;
  const int lane = threadIdx.x & 63;
  const int g = lane >> 4;
  const unsigned qb = (unsigned)(lane & 15) << 4;
  f32x2 acc[4];
#pragma unroll
  for (int k = 0; k < 4; ++k) acc[k] = (f32x2){0.f, 0.f};
  seg_accum<4>(ptrA, prA, (const char*)XA, qb, wid, g, acc);
  seg_accum<1>(ptrB, prB, (const char*)XB, qb, wid, g, acc);
#pragma unroll
  for (int k = 0; k < 4; ++k) {
    acc[k].x += __shfl_xor(acc[k].x, 16);
    acc[k].y += __shfl_xor(acc[k].y, 16);
    acc[k].x += __shfl_xor(acc[k].x, 32);
    acc[k].y += __shfl_xor(acc[k].y, 32);
  }
  if (g == 0) {
#pragma unroll
    for (int k = 0; k < 4; ++k) {
      acc[k].x = 1.f / (1.f + __expf(-acc[k].x));
      acc[k].y = 1.f / (1.f + __expf(-acc[k].y));
    }
    float4* yp = (float4*)(Y + (size_t)wid * CF + (qb >> 1));
    yp[0] = make_float4(acc[0].x, acc[0].y, acc[1].x, acc[1].y);
    yp[1] = make_float4(acc[2].x, acc[2].y, acc[3].x, acc[3].y);
  }
}

// ---------------------------------------------------------------------------
extern "C" void kernel_launch(void* const* d_in, const int* in_sizes, int n_in,
                              void* d_out, int out_size, void* d_ws, size_t ws_size,
                              hipStream_t stream) {
  const float* x      = (const float*)d_in[0];
  const float* W1_00  = (const float*)d_in[1];
  const float* W1_01  = (const float*)d_in[2];
  const float* W2_00  = (const float*)d_in[3];
  const float* W2_10  = (const float*)d_in[4];
  const int*   adj_rows = (const int*)d_in[5];
  const int*   adj_cols = (const int*)d_in[6];
  const float* adj_vals = (const float*)d_in[7];
  const int*   inc_rows = (const int*)d_in[8];
  const int*   inc_cols = (const int*)d_in[9];
  const float* inc_vals = (const float*)d_in[10];

  const int adj_nnz = in_sizes[5];       // 3,200,000
  const int inc_nnz = in_sizes[8];       // 400,000
  const int NN = in_sizes[0] / CF;       // 100,000 nodes
  const int EN = 200000;                 // edges (problem constant)

  const long long NE = (long long)NN * CF;   // node features
  const long long EE = (long long)EN * CF;   // edge features
  const int PN = ((NN + 2) & ~1);            // padded (8B-align int2 arrays)
  const int PE = ((EN + 2) & ~1);

  // ---- workspace layout ----
  unsigned short* tA = (unsigned short*)d_ws;   // NE bf16 ; prT alias at build
  unsigned short* n1 = tA + NE;                 // NE bf16 ; prT spill region
  unsigned short* e1 = n1 + NE;                 // EE bf16 ; cnt/S alias at build
  int*   ptr_a = (int*)(e1 + EE);
  int*   cur_a = ptr_a + PN;                    // (unused, layout stability)
  int2*  pr_a  = (int2*)(cur_a + PN);
  int*   ptr_e = (int*)(pr_a + adj_nnz);
  int*   cur_e = ptr_e + PE;                    // (unused)
  int2*  pr_e  = (int2*)(cur_e + PE);
  int*   ptr_i = (int*)(pr_e + inc_nnz);
  int*   cur_i = ptr_i + PN;                    // (unused)
  int2*  pr_i  = (int2*)(cur_i + PN);
  int*   blks  = (int*)(pr_i + inc_nnz);        // 2048 ints
  short* wp = (short*)(((uintptr_t)(blks + 2048) + 63) & ~(uintptr_t)63);
  short* w00 = wp;             // hi at +0, lo at +16384
  short* w01 = wp + 2 * 16384;
  short* w20 = wp + 4 * 16384;
  short* w21 = wp + 6 * 16384;

  // build-time scratch aliased onto feature buffers (dead until GEMMs/SpMMs):
  int2* prT  = (int2*)tA;
  int*  cntA = (int*)e1;
  int*  SA   = cntA + 1600512;

  unsigned short* t1 = (unsigned short*)d_out;  // bf16 scratch; dead before final write
  float* outf = (float*)d_out;

  const dim3 blk(256);
  const int gN = (NN + 63) / 64;                // 1563
  const int gE = (EN + 63) / 64;                // 3125
  const int nbukN = (NN + RB - 1) >> RB_SHIFT;  // 1563
  const int nbukE = (EN + RB - 1) >> RB_SHIFT;  // 3125
  const int totbuk = nbukN + nbukE + nbukN;     // 6251
  const int nS = totbuk * NPASSBLK + 1;         // 1,600,257
  const int nbS = (nS + 1023) / 1024;           // 1563 (<= 2048 scan_sums cap)
  const int ldsbk = nbukE * 4;                  // max bucket count LDS bytes

  // ---- pack weights (1) ----
  pack_w4<<<32, blk, 0, stream>>>(W1_00, W1_01, W2_00, W2_10, wp);

  // ---- fused CSR builds (2-7): count3, scan x3, scatter3, to_csr3 ----
  bucket_count3<<<3 * NPASSBLK, dim3(BT), ldsbk, stream>>>(
      adj_rows, inc_cols, inc_rows, cntA,
      adj_nnz, inc_nnz, inc_nnz, nbukN, nbukE, nbukN);
  scan_block<<<nbS, blk, 0, stream>>>(cntA, SA, blks, nS);
  scan_sums<<<1, blk, 0, stream>>>(blks, nbS);
  scan_add<<<nbS, blk, 0, stream>>>(SA, blks, nS);
  bucket_scatter3<<<3 * NPASSBLK, dim3(BT), ldsbk, stream>>>(
      adj_rows, adj_cols, adj_vals,
      inc_cols, inc_rows, inc_vals,
      inc_rows, inc_cols, inc_vals,
      SA, prT, adj_nnz, inc_nnz, inc_nnz, nbukN, nbukE, nbukN);
  bucket_to_csr3<<<totbuk, blk, 0, stream>>>(
      SA, prT, pr_a, ptr_a, pr_e, ptr_e, pr_i, ptr_i,
      NN, EN, NN, nbukN, nbukE, adj_nnz, inc_nnz);

  // ---- level 1 GEMMs fused (8): t1 = x@W1_00, tA = x@W1_01 ----
  gemm_f32_l1<<<2 * gN, dim3(128), 0, stream>>>(x, w00, w01, t1, tA, NN, gN);

  // ---- level 1 SpMMs fused (9): n1 = sig(adj-seg t1), e1 = sig(incT-seg tA) --
  const int spN = (NN + 3) / 4;
  const int spE4 = (EN + 15) / 16;              // quad-row: 16 rows per block
  csr_spmm_l1<<<spN + spE4, blk, 0, stream>>>(
      ptr_a, pr_a, (const unsigned*)t1, (unsigned*)n1, NN,
      ptr_e, pr_e, (const unsigned*)tA, (unsigned*)e1, EN, spN);

  // ---- level 2 GEMMs fused (10): n1 = n1@W2_00, e1 = e1@W2_10 (in-place) ----
  gemm_b16_l2<<<gN + gE, dim3(128), 0, stream>>>(
      (unsigned short*)n1, w20, (unsigned short*)e1, w21, NN, EN, gN);

  // ---- fused level-2 SpMMs + merge sigmoid (11) ----
  csr_spmm2_sig<<<spN, blk, 0, stream>>>(ptr_a, pr_a, (const unsigned*)n1,
                                         ptr_i, pr_i, (const unsigned*)e1, outf, NN);
}